// Round 10
// baseline (172.895 us; speedup 1.0000x reference)
//
#include <hip/hip_runtime.h>
#include <hip/hip_bf16.h>

// SAGAN self-attention, MI355X gfx950. B=4, C=64, H=W=128, N=16384, M=4096.
// fp32 in/out. Round 20: probe resolved the budget — proj = 6.6 µs (proj x2
// delta), attn = 47.6, harness-fixed ~63 µs. Single lever this round: R14's
// m-half attn (best, 47.4) with launch_bounds(512,6) -> 3 blocks/CU
// (LDS 3x40960 = 120K <= 160K; VGPR cap ~85 > 60 used, codegen unchanged).
// proj back to single launch (R13 verbatim).
// Layouts: 32x32x16 A[row=lane&31][k=8h+j], B[k=8h+j][col=lane&31]
// (h=lane>>5); C/D[row=(r&3)+8(r>>2)+4h][col=lane&31].

typedef __attribute__((ext_vector_type(16))) float f32x16;
typedef __attribute__((ext_vector_type(4))) float f32x4;
typedef __attribute__((ext_vector_type(2))) float f32x2;
typedef __attribute__((ext_vector_type(8))) short s16x8;

__device__ __forceinline__ unsigned short f32_bf16(float f) {
    unsigned int u = __float_as_uint(f);
    return (unsigned short)((u + 0x7fffu + ((u >> 16) & 1u)) >> 16);  // RNE
}
__device__ __forceinline__ unsigned int pk_bf16(float a, float b) {
    return (unsigned int)f32_bf16(a) | ((unsigned int)f32_bf16(b) << 16);
}
__device__ __forceinline__ unsigned int pk_rh(float a, float b) {   // round-half-up
    unsigned int au = __float_as_uint(a) + 0x8000u;
    unsigned int bu = __float_as_uint(b) + 0x8000u;
    return __builtin_amdgcn_perm(bu, au, 0x07060302u);
}
__device__ __forceinline__ unsigned int pk_tr(float a, float b) {   // truncate
    return __builtin_amdgcn_perm(__float_as_uint(b), __float_as_uint(a), 0x07060302u);
}
// async 16B/lane global->LDS DMA; lds dest = wave-uniform base + lane*16
__device__ __forceinline__ void async16(const void* g, void* l) {
    __builtin_amdgcn_global_load_lds(
        (const __attribute__((address_space(1))) unsigned int*)g,
        (__attribute__((address_space(3))) unsigned int*)l, 16, 0, 0);
}

// ---------------- proj: theta/phi/g 1x1 conv + 2x2 maxpool, MFMA ----------------
// (round 13 verbatim — passed; emits pi-permuted gG for the 32x32 PV)
__global__ __launch_bounds__(256) void proj_kernel(
    const float* __restrict__ x,
    const float* __restrict__ w_theta, const float* __restrict__ w_phi,
    const float* __restrict__ w_g,
    __hip_bfloat16* __restrict__ thG,   // [b][n][8]  (theta * log2e)
    __hip_bfloat16* __restrict__ phG,   // [b][m][8]
    __hip_bfloat16* __restrict__ gG)    // [b][32][4096], pi-permuted per 32-m chunk
{
    __shared__ __align__(16) unsigned short x_s[128 * 72];  // [pix][c], 144 B rows
    int tid = threadIdx.x;
    int bx = blockIdx.x;
    int b = bx >> 7, mh = (bx >> 1) & 63, ph = bx & 1;

    {   // phase 1: float4 loads (c-pair per thread), packed u32 LDS transpose
        int cp = tid >> 3, s = tid & 7;
        const float* xb = x + ((size_t)b << 20) + (size_t)(2 * mh) * 128 + 64 * ph;
        const float* p0r = xb + ((size_t)(2 * cp) << 14);
        const float* p1r = p0r + (1 << 14);
#pragma unroll
        for (int py = 0; py < 2; py++)
#pragma unroll
            for (int t = 0; t < 2; t++) {
                int pxl = 4 * s + 32 * t;
                float4 a = *(const float4*)(p0r + py * 128 + pxl);
                float4 c = *(const float4*)(p1r + py * 128 + pxl);
                int pix = py * 64 + pxl;
                *(unsigned int*)&x_s[(pix + 0) * 72 + 2 * cp] = pk_rh(a.x, c.x);
                *(unsigned int*)&x_s[(pix + 1) * 72 + 2 * cp] = pk_rh(a.y, c.y);
                *(unsigned int*)&x_s[(pix + 2) * 72 + 2 * cp] = pk_rh(a.z, c.z);
                *(unsigned int*)&x_s[(pix + 3) * 72 + 2 * cp] = pk_rh(a.w, c.w);
            }
    }

    int lane = tid & 63, w = tid >> 6;
    int q = lane >> 4, nl = lane & 15;

    s16x8 A[3][2];
#pragma unroll
    for (int CT = 0; CT < 3; CT++) {
        const float* wsrc;
        float scale = 1.0f;
        if (CT == 0) {
            if (nl < 8) { wsrc = w_theta + nl * 64; scale = 1.44269504f; }
            else        { wsrc = w_phi + (nl - 8) * 64; }
        } else if (CT == 1) wsrc = w_g + nl * 64;
        else                wsrc = w_g + (16 + nl) * 64;
#pragma unroll
        for (int ks = 0; ks < 2; ks++) {
            const float4* p4 = (const float4*)(wsrc + 32 * ks + 8 * q);
            float4 a0 = p4[0], a1 = p4[1];
            s16x8 f;
            f[0] = (short)f32_bf16(a0.x * scale); f[1] = (short)f32_bf16(a0.y * scale);
            f[2] = (short)f32_bf16(a0.z * scale); f[3] = (short)f32_bf16(a0.w * scale);
            f[4] = (short)f32_bf16(a1.x * scale); f[5] = (short)f32_bf16(a1.y * scale);
            f[6] = (short)f32_bf16(a1.z * scale); f[7] = (short)f32_bf16(a1.w * scale);
            A[CT][ks] = f;
        }
    }
    __syncthreads();

    f32x4 acc[3][2];
#pragma unroll
    for (int ti = 0; ti < 2; ti++) {
        int tile = w + 4 * ti;
        const unsigned short* rb = x_s + (16 * tile + nl) * 72;
        s16x8 B0 = *(const s16x8*)(rb + 8 * q);
        s16x8 B1 = *(const s16x8*)(rb + 32 + 8 * q);
#pragma unroll
        for (int CT = 0; CT < 3; CT++) {
            f32x4 d = (f32x4){0.f, 0.f, 0.f, 0.f};
            d = __builtin_amdgcn_mfma_f32_16x16x32_bf16(A[CT][0], B0, d, 0, 0, 0);
            d = __builtin_amdgcn_mfma_f32_16x16x32_bf16(A[CT][1], B1, d, 0, 0, 0);
            acc[CT][ti] = d;
        }
    }

    if (q < 2) {
        unsigned short* thb = (unsigned short*)thG + ((size_t)b << 14) * 8;
#pragma unroll
        for (int ti = 0; ti < 2; ti++) {
            int n = (2 * mh + ti) * 128 + 64 * ph + 16 * w + nl;
            uint2 tv;
            tv.x = pk_bf16(acc[0][ti][0], acc[0][ti][1]);
            tv.y = pk_bf16(acc[0][ti][2], acc[0][ti][3]);
            *(uint2*)(thb + (size_t)n * 8 + 4 * q) = tv;
        }
    }

    float pool[3][4];
#pragma unroll
    for (int CT = 0; CT < 3; CT++)
#pragma unroll
        for (int r = 0; r < 4; r++) {
            float a = fmaxf(acc[CT][0][r], acc[CT][1][r]);
            pool[CT][r] = fmaxf(a, __shfl_xor(a, 1));
        }

    int mm = 8 * w + (nl >> 1);
    int mbase = mh * 64 + ph * 32;
    if ((nl & 1) == 0) {
        if (q >= 2) {
            uint2 pv;
            pv.x = pk_bf16(pool[0][0], pool[0][1]);
            pv.y = pk_bf16(pool[0][2], pool[0][3]);
            *(uint2*)((unsigned short*)phG + ((size_t)(b * 4096 + mbase + mm)) * 8 + (q - 2) * 4) = pv;
        }
        // pi for 32x32 PV A-frags: i = 16*((mm>>4)&1) + 8*((mm>>2)&1) + 4*((mm>>3)&1) + (mm&3)
        int p = 16 * ((mm >> 4) & 1) + 8 * ((mm >> 2) & 1) + 4 * ((mm >> 3) & 1) + (mm & 3);
        int mstore = mbase + p;
#pragma unroll
        for (int CT = 1; CT < 3; CT++)
#pragma unroll
            for (int r = 0; r < 4; r++) {
                int cg = 16 * (CT - 1) + 4 * q + r;
                ((unsigned short*)gG)[((size_t)(b * 32 + cg) << 12) + mstore] =
                    f32_bf16(pool[CT][r]);
            }
    }
}

// ---------------- attn: m-split 8-wave, 32x32x16 score -> exp2 -> 2x PV --------
// (R14 structure — best measured attn; launch_bounds(512,6) for 3 blocks/CU)
// Grid 512 = b(4) x n-tile(128). Block 512 thr = 2 m-halves x 4 waves x 32 n.
// Each half: 16 sts x 128 m-cols. LDS per half: g dbuf 2x8192 + phi dbuf 2x2048.
// Map: gA[0,16384) gB[16384,32768) pA[32768,36864) pB[36864,40960).
__global__ __launch_bounds__(512, 6) void attn_kernel(
    const __hip_bfloat16* __restrict__ thG, const __hip_bfloat16* __restrict__ phG,
    const __hip_bfloat16* __restrict__ gG,
    const float* __restrict__ w_o, const float* __restrict__ gamma,
    const float* __restrict__ x, float* __restrict__ out)
{
    __shared__ __align__(64) unsigned char smem[40960];

    int tid = threadIdx.x, lane = tid & 63, w = tid >> 6;   // w: 0..7
    int w4 = w & 3, hf = w >> 2;
    int q = lane >> 4, nl = lane & 15;
    int c31 = lane & 31, h = lane >> 5;
    int bx = blockIdx.x;
    int b  = bx >> 7;
    int n0 = (bx & 127) << 7;
    int nw = n0 + w4 * 32;

    const unsigned short* thb = (const unsigned short*)thG + ((size_t)b << 14) * 8;
    const unsigned short* phb = (const unsigned short*)phG + ((size_t)b << 12) * 8;
    const unsigned short* ggb = (const unsigned short*)gG + ((size_t)b << 17);

    // theta B-frag (32x32x16): B[k=c=8h+j][col=n=c31]; h=1/j=0 = bias slot
    s16x8 BT = (s16x8){0, 0, 0, 0, 0, 0, 0, 0};
    if (h == 0) BT = *(const s16x8*)(thb + (size_t)(nw + c31) * 8);
    else        BT[0] = (short)0xC167;   // bf16(-14.4375)
    // phi A-frag const part: h=1/j=0 -> k=8 slot = 1.0
    s16x8 Fc = (s16x8){0, 0, 0, 0, 0, 0, 0, 0};
    if (h == 1) Fc[0] = (short)0x3F80;

    f32x16 acc = {};          // PV acc: [row=c=(r&3)+8(r>>2)+4h][col=n=c31]
    f32x2  l2 = (f32x2){0.f, 0.f};

    // staging: per wave 2 g-calls (rows 8w4..+3, 8w4+4..+7 of this half's st) +
    // phi (waves w4<2). LDS slot s of row r holds logical slot s^(r&15).
    int rA = 8 * w4 + (lane >> 4);       // k=0 rows
    int rB = rA + 4;                     // k=1 rows
    const unsigned short* gsrcA = ggb + ((size_t)rA << 12) + (hf << 11)
                                  + (((lane & 15) ^ (rA & 15)) << 3);
    const unsigned short* gsrcB = ggb + ((size_t)rB << 12) + (hf << 11)
                                  + (((lane & 15) ^ (rB & 15)) << 3);
    const unsigned short* psrc  = phb + (size_t)((hf << 11) + w4 * 64 + lane) * 8;
    unsigned char* gdst = smem + hf * 16384 + w4 * 2048;        // + k*1024 + buf*8192
    unsigned char* pdst = smem + 32768 + hf * 4096 + w4 * 1024; // + buf*2048 (w4<2)

    // pre-stage st 0 -> buf 0
    async16(gsrcA, gdst);
    async16(gsrcB, gdst + 1024);
    if (w4 < 2) async16(psrc, pdst);
    __syncthreads();

    for (int st = 0; st < 16; st++) {
        const unsigned char* gcur = smem + hf * 16384 + (st & 1) * 8192;
        const unsigned char* pcur = smem + 32768 + hf * 4096 + (st & 1) * 2048;
        if (st < 15) {   // issue next st's DMA into the other buffers (no wait)
            int nb = (st + 1) & 1;
            int mo = (st + 1) << 7;           // g element offset (128/st)
            async16(gsrcA + mo, gdst + nb * 8192);
            async16(gsrcB + mo, gdst + nb * 8192 + 1024);
            if (w4 < 2) async16(psrc + (size_t)mo * 8, pdst + nb * 2048);
        }
#pragma unroll
        for (int t8 = 0; t8 < 4; t8++) {
            int mloc = t8 << 5;
            // phi A-frag: rows mloc..mloc+31 of this st (contiguous 16B)
            s16x8 F = Fc;
            if (h == 0) F = *(const s16x8*)(pcur + (mloc + c31) * 16);
            // G A-frags: logical slot 4*t8+2*pv+h, LDS slot = logical^(c31&15)
            int s0 = (t8 << 2) + h;
            int m15 = c31 & 15;
            s16x8 G1 = *(const s16x8*)(gcur + c31 * 256 + (((s0 + 0) ^ m15) << 4));
            s16x8 G2 = *(const s16x8*)(gcur + c31 * 256 + (((s0 + 2) ^ m15) << 4));

            f32x16 z = {};
            f32x16 S = __builtin_amdgcn_mfma_f32_32x32x16_bf16(F, BT, z, 0, 0, 0);

            float p0  = __builtin_amdgcn_exp2f(S[0]);
            float p1  = __builtin_amdgcn_exp2f(S[1]);
            float p2  = __builtin_amdgcn_exp2f(S[2]);
            float p3  = __builtin_amdgcn_exp2f(S[3]);
            float p4  = __builtin_amdgcn_exp2f(S[4]);
            float p5  = __builtin_amdgcn_exp2f(S[5]);
            float p6  = __builtin_amdgcn_exp2f(S[6]);
            float p7  = __builtin_amdgcn_exp2f(S[7]);
            float p8  = __builtin_amdgcn_exp2f(S[8]);
            float p9  = __builtin_amdgcn_exp2f(S[9]);
            float p10 = __builtin_amdgcn_exp2f(S[10]);
            float p11 = __builtin_amdgcn_exp2f(S[11]);
            float p12 = __builtin_amdgcn_exp2f(S[12]);
            float p13 = __builtin_amdgcn_exp2f(S[13]);
            float p14 = __builtin_amdgcn_exp2f(S[14]);
            float p15 = __builtin_amdgcn_exp2f(S[15]);

            // denominator on VALU: packed-f32 add tree (7 pk-adds)
            f32x2 u0 = (f32x2){p0, p1} + (f32x2){p2, p3};
            f32x2 u1 = (f32x2){p4, p5} + (f32x2){p6, p7};
            f32x2 u2 = (f32x2){p8, p9} + (f32x2){p10, p11};
            f32x2 u3 = (f32x2){p12, p13} + (f32x2){p14, p15};
            l2 += (u0 + u1) + (u2 + u3);

            // B-frags: direct in-lane packs (pi makes k-order = reg-order)
            uint4 ub1 = make_uint4(pk_tr(p0, p1), pk_tr(p2, p3),
                                   pk_tr(p4, p5), pk_tr(p6, p7));
            uint4 ub2 = make_uint4(pk_tr(p8, p9), pk_tr(p10, p11),
                                   pk_tr(p12, p13), pk_tr(p14, p15));
            s16x8 B1 = *(s16x8*)&ub1;
            s16x8 B2 = *(s16x8*)&ub2;

            acc = __builtin_amdgcn_mfma_f32_32x32x16_bf16(G1, B1, acc, 0, 0, 0);
            acc = __builtin_amdgcn_mfma_f32_32x32x16_bf16(G2, B2, acc, 0, 0, 0);
        }
        __syncthreads();   // single barrier/st; drains next-st DMA (vmcnt) too
    }

    // per-half denominator: combine h-halves (h=0: m%8<4, h=1: rest)
    float l = l2[0] + l2[1];
    l += __shfl_xor(l, 32);

    // cross-half combine: half 1 dumps partials into now-free staging LDS
    int idx = (w4 << 6) + lane;          // 0..255, lane-aligned across halves
    if (hf == 1) {
        *(f32x16*)(smem + idx * 64) = acc;                 // [0,16384)
        *(float*)(smem + 32768 + idx * 4) = l;             // pA buf0, 1 KB
    }
    __syncthreads();
    if (hf == 0) {
        f32x16 accB = *(const f32x16*)(smem + idx * 64);
        float lB = *(const float*)(smem + 32768 + idx * 4);
        acc += accB;
        float linv = 1.0f / (l + lB);
        acc *= linv;

        // w_o A-frags: A[row=cc=16g4+nl][k=c=8q+j]
        s16x8 WO[4];
#pragma unroll
        for (int g4 = 0; g4 < 4; g4++) {
            const float4* wr = (const float4*)(w_o + (size_t)(g4 * 16 + nl) * 32 + q * 8);
            float4 a0 = wr[0], a1 = wr[1];
            WO[g4][0] = (short)f32_bf16(a0.x); WO[g4][1] = (short)f32_bf16(a0.y);
            WO[g4][2] = (short)f32_bf16(a0.z); WO[g4][3] = (short)f32_bf16(a0.w);
            WO[g4][4] = (short)f32_bf16(a1.x); WO[g4][5] = (short)f32_bf16(a1.y);
            WO[g4][6] = (short)f32_bf16(a1.z); WO[g4][7] = (short)f32_bf16(a1.w);
        }
        float gam = gamma[0];

        // O_s overlay [128][80 B] at 20480 (free; no overlap with dump/l regions)
        unsigned char* O_s = smem + 20480;
        int nloc = w4 * 32 + c31;
#pragma unroll
        for (int g2 = 0; g2 < 4; g2++) {
            uint2 ov;
            ov.x = pk_bf16(acc[4 * g2 + 0], acc[4 * g2 + 1]);
            ov.y = pk_bf16(acc[4 * g2 + 2], acc[4 * g2 + 3]);
            *(uint2*)(O_s + nloc * 80 + 16 * g2 + 8 * h) = ov;
        }
        int nloc0 = w4 * 32 + nl;
        int nloc1 = nloc0 + 16;
        s16x8 OB0 = *(const s16x8*)(O_s + nloc0 * 80 + q * 16);  // wave-local rows
        s16x8 OB1 = *(const s16x8*)(O_s + nloc1 * 80 + q * 16);
#pragma unroll
        for (int g4 = 0; g4 < 4; g4++) {
            f32x4 e0 = (f32x4){0.f, 0.f, 0.f, 0.f};
            f32x4 e1 = (f32x4){0.f, 0.f, 0.f, 0.f};
            e0 = __builtin_amdgcn_mfma_f32_16x16x32_bf16(WO[g4], OB0, e0, 0, 0, 0);
            e1 = __builtin_amdgcn_mfma_f32_16x16x32_bf16(WO[g4], OB1, e1, 0, 0, 0);
#pragma unroll
            for (int r = 0; r < 4; r++) {
                int cc = g4 * 16 + q * 4 + r;
                size_t gi0 = (((size_t)(b * 64 + cc)) << 14) + nw + nl;
                out[gi0] = gam * e0[r] + x[gi0];
                size_t gi1 = gi0 + 16;
                out[gi1] = gam * e1[r] + x[gi1];
            }
        }
    }
}

extern "C" void kernel_launch(void* const* d_in, const int* in_sizes, int n_in,
                              void* d_out, int out_size, void* d_ws, size_t ws_size,
                              hipStream_t stream) {
    const float* x       = (const float*)d_in[0];
    const float* w_theta = (const float*)d_in[1];
    const float* w_phi   = (const float*)d_in[2];
    const float* w_g     = (const float*)d_in[3];
    const float* w_o     = (const float*)d_in[4];
    const float* gamma   = (const float*)d_in[5];
    float* out = (float*)d_out;

    __hip_bfloat16* thG = (__hip_bfloat16*)d_ws;        // 4*16384*8 = 1 MB
    __hip_bfloat16* phG = thG + 524288;                 // 4*4096*8  = 256 KB
    __hip_bfloat16* gG  = phG + 131072;                 // 4*32*4096 = 1 MB

    proj_kernel<<<512, 256, 0, stream>>>(x, w_theta, w_phi, w_g, thG, phG, gG);
    attn_kernel<<<512, 512, 0, stream>>>(thG, phG, gG, w_o, gamma, x, out);
}

// Round 12
// 117.767 us; speedup vs baseline: 1.4681x; 1.4681x over previous
//
#include <hip/hip_runtime.h>
#include <hip/hip_bf16.h>

// SAGAN self-attention, MI355X gfx950. B=4, C=64, H=W=128, N=16384, M=4096.
// fp32 in/out. Round 22 (resubmit after GPU acquisition timeout): PURE REVERT
// to best measured configuration. R20's launch_bounds(512,6) spilled
// catastrophically (VGPR pinned 40, WRITE_SIZE 178 MB, attn 100+ µs) — third
// falsification of the "launch_bounds is a free occupancy dial" model.
// Validated config: R13 proj (6.6 µs, probe-measured) + R14 attn (47.4 µs,
// launch_bounds(512,4), VGPR 60, no spills). Budget: harness ~63 + proj 6.6
// + attn 47.4 = ~117 µs. This text is byte-identical to the R4/117.4 µs kernel.
// Layouts: 32x32x16 A[row=lane&31][k=8h+j], B[k=8h+j][col=lane&31]
// (h=lane>>5); C/D[row=(r&3)+8(r>>2)+4h][col=lane&31].

typedef __attribute__((ext_vector_type(16))) float f32x16;
typedef __attribute__((ext_vector_type(4))) float f32x4;
typedef __attribute__((ext_vector_type(2))) float f32x2;
typedef __attribute__((ext_vector_type(8))) short s16x8;

__device__ __forceinline__ unsigned short f32_bf16(float f) {
    unsigned int u = __float_as_uint(f);
    return (unsigned short)((u + 0x7fffu + ((u >> 16) & 1u)) >> 16);  // RNE
}
__device__ __forceinline__ unsigned int pk_bf16(float a, float b) {
    return (unsigned int)f32_bf16(a) | ((unsigned int)f32_bf16(b) << 16);
}
__device__ __forceinline__ unsigned int pk_rh(float a, float b) {   // round-half-up
    unsigned int au = __float_as_uint(a) + 0x8000u;
    unsigned int bu = __float_as_uint(b) + 0x8000u;
    return __builtin_amdgcn_perm(bu, au, 0x07060302u);
}
__device__ __forceinline__ unsigned int pk_tr(float a, float b) {   // truncate
    return __builtin_amdgcn_perm(__float_as_uint(b), __float_as_uint(a), 0x07060302u);
}
// async 16B/lane global->LDS DMA; lds dest = wave-uniform base + lane*16
__device__ __forceinline__ void async16(const void* g, void* l) {
    __builtin_amdgcn_global_load_lds(
        (const __attribute__((address_space(1))) unsigned int*)g,
        (__attribute__((address_space(3))) unsigned int*)l, 16, 0, 0);
}

// ---------------- proj: theta/phi/g 1x1 conv + 2x2 maxpool, MFMA ----------------
// (round 13 verbatim — passed; emits pi-permuted gG for the 32x32 PV)
__global__ __launch_bounds__(256) void proj_kernel(
    const float* __restrict__ x,
    const float* __restrict__ w_theta, const float* __restrict__ w_phi,
    const float* __restrict__ w_g,
    __hip_bfloat16* __restrict__ thG,   // [b][n][8]  (theta * log2e)
    __hip_bfloat16* __restrict__ phG,   // [b][m][8]
    __hip_bfloat16* __restrict__ gG)    // [b][32][4096], pi-permuted per 32-m chunk
{
    __shared__ __align__(16) unsigned short x_s[128 * 72];  // [pix][c], 144 B rows
    int tid = threadIdx.x;
    int bx = blockIdx.x;
    int b = bx >> 7, mh = (bx >> 1) & 63, ph = bx & 1;

    {   // phase 1: float4 loads (c-pair per thread), packed u32 LDS transpose
        int cp = tid >> 3, s = tid & 7;
        const float* xb = x + ((size_t)b << 20) + (size_t)(2 * mh) * 128 + 64 * ph;
        const float* p0r = xb + ((size_t)(2 * cp) << 14);
        const float* p1r = p0r + (1 << 14);
#pragma unroll
        for (int py = 0; py < 2; py++)
#pragma unroll
            for (int t = 0; t < 2; t++) {
                int pxl = 4 * s + 32 * t;
                float4 a = *(const float4*)(p0r + py * 128 + pxl);
                float4 c = *(const float4*)(p1r + py * 128 + pxl);
                int pix = py * 64 + pxl;
                *(unsigned int*)&x_s[(pix + 0) * 72 + 2 * cp] = pk_rh(a.x, c.x);
                *(unsigned int*)&x_s[(pix + 1) * 72 + 2 * cp] = pk_rh(a.y, c.y);
                *(unsigned int*)&x_s[(pix + 2) * 72 + 2 * cp] = pk_rh(a.z, c.z);
                *(unsigned int*)&x_s[(pix + 3) * 72 + 2 * cp] = pk_rh(a.w, c.w);
            }
    }

    int lane = tid & 63, w = tid >> 6;
    int q = lane >> 4, nl = lane & 15;

    s16x8 A[3][2];
#pragma unroll
    for (int CT = 0; CT < 3; CT++) {
        const float* wsrc;
        float scale = 1.0f;
        if (CT == 0) {
            if (nl < 8) { wsrc = w_theta + nl * 64; scale = 1.44269504f; }
            else        { wsrc = w_phi + (nl - 8) * 64; }
        } else if (CT == 1) wsrc = w_g + nl * 64;
        else                wsrc = w_g + (16 + nl) * 64;
#pragma unroll
        for (int ks = 0; ks < 2; ks++) {
            const float4* p4 = (const float4*)(wsrc + 32 * ks + 8 * q);
            float4 a0 = p4[0], a1 = p4[1];
            s16x8 f;
            f[0] = (short)f32_bf16(a0.x * scale); f[1] = (short)f32_bf16(a0.y * scale);
            f[2] = (short)f32_bf16(a0.z * scale); f[3] = (short)f32_bf16(a0.w * scale);
            f[4] = (short)f32_bf16(a1.x * scale); f[5] = (short)f32_bf16(a1.y * scale);
            f[6] = (short)f32_bf16(a1.z * scale); f[7] = (short)f32_bf16(a1.w * scale);
            A[CT][ks] = f;
        }
    }
    __syncthreads();

    f32x4 acc[3][2];
#pragma unroll
    for (int ti = 0; ti < 2; ti++) {
        int tile = w + 4 * ti;
        const unsigned short* rb = x_s + (16 * tile + nl) * 72;
        s16x8 B0 = *(const s16x8*)(rb + 8 * q);
        s16x8 B1 = *(const s16x8*)(rb + 32 + 8 * q);
#pragma unroll
        for (int CT = 0; CT < 3; CT++) {
            f32x4 d = (f32x4){0.f, 0.f, 0.f, 0.f};
            d = __builtin_amdgcn_mfma_f32_16x16x32_bf16(A[CT][0], B0, d, 0, 0, 0);
            d = __builtin_amdgcn_mfma_f32_16x16x32_bf16(A[CT][1], B1, d, 0, 0, 0);
            acc[CT][ti] = d;
        }
    }

    if (q < 2) {
        unsigned short* thb = (unsigned short*)thG + ((size_t)b << 14) * 8;
#pragma unroll
        for (int ti = 0; ti < 2; ti++) {
            int n = (2 * mh + ti) * 128 + 64 * ph + 16 * w + nl;
            uint2 tv;
            tv.x = pk_bf16(acc[0][ti][0], acc[0][ti][1]);
            tv.y = pk_bf16(acc[0][ti][2], acc[0][ti][3]);
            *(uint2*)(thb + (size_t)n * 8 + 4 * q) = tv;
        }
    }

    float pool[3][4];
#pragma unroll
    for (int CT = 0; CT < 3; CT++)
#pragma unroll
        for (int r = 0; r < 4; r++) {
            float a = fmaxf(acc[CT][0][r], acc[CT][1][r]);
            pool[CT][r] = fmaxf(a, __shfl_xor(a, 1));
        }

    int mm = 8 * w + (nl >> 1);
    int mbase = mh * 64 + ph * 32;
    if ((nl & 1) == 0) {
        if (q >= 2) {
            uint2 pv;
            pv.x = pk_bf16(pool[0][0], pool[0][1]);
            pv.y = pk_bf16(pool[0][2], pool[0][3]);
            *(uint2*)((unsigned short*)phG + ((size_t)(b * 4096 + mbase + mm)) * 8 + (q - 2) * 4) = pv;
        }
        // pi for 32x32 PV A-frags: i = 16*((mm>>4)&1) + 8*((mm>>2)&1) + 4*((mm>>3)&1) + (mm&3)
        int p = 16 * ((mm >> 4) & 1) + 8 * ((mm >> 2) & 1) + 4 * ((mm >> 3) & 1) + (mm & 3);
        int mstore = mbase + p;
#pragma unroll
        for (int CT = 1; CT < 3; CT++)
#pragma unroll
            for (int r = 0; r < 4; r++) {
                int cg = 16 * (CT - 1) + 4 * q + r;
                ((unsigned short*)gG)[((size_t)(b * 32 + cg) << 12) + mstore] =
                    f32_bf16(pool[CT][r]);
            }
    }
}

// ---------------- attn: m-split 8-wave, 32x32x16 score -> exp2 -> 2x PV --------
// (R14 verbatim — best measured attn, 47.4 µs, VGPR 60, no spills)
// Grid 512 = b(4) x n-tile(128). Block 512 thr = 2 m-halves x 4 waves x 32 n.
// Each half: 16 sts x 128 m-cols. LDS per half: g dbuf 2x8192 + phi dbuf 2x2048.
// Map: gA[0,16384) gB[16384,32768) pA[32768,36864) pB[36864,40960).
__global__ __launch_bounds__(512, 4) void attn_kernel(
    const __hip_bfloat16* __restrict__ thG, const __hip_bfloat16* __restrict__ phG,
    const __hip_bfloat16* __restrict__ gG,
    const float* __restrict__ w_o, const float* __restrict__ gamma,
    const float* __restrict__ x, float* __restrict__ out)
{
    __shared__ __align__(64) unsigned char smem[40960];

    int tid = threadIdx.x, lane = tid & 63, w = tid >> 6;   // w: 0..7
    int w4 = w & 3, hf = w >> 2;
    int q = lane >> 4, nl = lane & 15;
    int c31 = lane & 31, h = lane >> 5;
    int bx = blockIdx.x;
    int b  = bx >> 7;
    int n0 = (bx & 127) << 7;
    int nw = n0 + w4 * 32;

    const unsigned short* thb = (const unsigned short*)thG + ((size_t)b << 14) * 8;
    const unsigned short* phb = (const unsigned short*)phG + ((size_t)b << 12) * 8;
    const unsigned short* ggb = (const unsigned short*)gG + ((size_t)b << 17);

    // theta B-frag (32x32x16): B[k=c=8h+j][col=n=c31]; h=1/j=0 = bias slot
    s16x8 BT = (s16x8){0, 0, 0, 0, 0, 0, 0, 0};
    if (h == 0) BT = *(const s16x8*)(thb + (size_t)(nw + c31) * 8);
    else        BT[0] = (short)0xC167;   // bf16(-14.4375)
    // phi A-frag const part: h=1/j=0 -> k=8 slot = 1.0
    s16x8 Fc = (s16x8){0, 0, 0, 0, 0, 0, 0, 0};
    if (h == 1) Fc[0] = (short)0x3F80;

    f32x16 acc = {};          // PV acc: [row=c=(r&3)+8(r>>2)+4h][col=n=c31]
    f32x2  l2 = (f32x2){0.f, 0.f};

    // staging: per wave 2 g-calls (rows 8w4..+3, 8w4+4..+7 of this half's st) +
    // phi (waves w4<2). LDS slot s of row r holds logical slot s^(r&15).
    int rA = 8 * w4 + (lane >> 4);       // k=0 rows
    int rB = rA + 4;                     // k=1 rows
    const unsigned short* gsrcA = ggb + ((size_t)rA << 12) + (hf << 11)
                                  + (((lane & 15) ^ (rA & 15)) << 3);
    const unsigned short* gsrcB = ggb + ((size_t)rB << 12) + (hf << 11)
                                  + (((lane & 15) ^ (rB & 15)) << 3);
    const unsigned short* psrc  = phb + (size_t)((hf << 11) + w4 * 64 + lane) * 8;
    unsigned char* gdst = smem + hf * 16384 + w4 * 2048;        // + k*1024 + buf*8192
    unsigned char* pdst = smem + 32768 + hf * 4096 + w4 * 1024; // + buf*2048 (w4<2)

    // pre-stage st 0 -> buf 0
    async16(gsrcA, gdst);
    async16(gsrcB, gdst + 1024);
    if (w4 < 2) async16(psrc, pdst);
    __syncthreads();

    for (int st = 0; st < 16; st++) {
        const unsigned char* gcur = smem + hf * 16384 + (st & 1) * 8192;
        const unsigned char* pcur = smem + 32768 + hf * 4096 + (st & 1) * 2048;
        if (st < 15) {   // issue next st's DMA into the other buffers (no wait)
            int nb = (st + 1) & 1;
            int mo = (st + 1) << 7;           // g element offset (128/st)
            async16(gsrcA + mo, gdst + nb * 8192);
            async16(gsrcB + mo, gdst + nb * 8192 + 1024);
            if (w4 < 2) async16(psrc + (size_t)mo * 8, pdst + nb * 2048);
        }
#pragma unroll
        for (int t8 = 0; t8 < 4; t8++) {
            int mloc = t8 << 5;
            // phi A-frag: rows mloc..mloc+31 of this st (contiguous 16B)
            s16x8 F = Fc;
            if (h == 0) F = *(const s16x8*)(pcur + (mloc + c31) * 16);
            // G A-frags: logical slot 4*t8+2*pv+h, LDS slot = logical^(c31&15)
            int s0 = (t8 << 2) + h;
            int m15 = c31 & 15;
            s16x8 G1 = *(const s16x8*)(gcur + c31 * 256 + (((s0 + 0) ^ m15) << 4));
            s16x8 G2 = *(const s16x8*)(gcur + c31 * 256 + (((s0 + 2) ^ m15) << 4));

            f32x16 z = {};
            f32x16 S = __builtin_amdgcn_mfma_f32_32x32x16_bf16(F, BT, z, 0, 0, 0);

            float p0  = __builtin_amdgcn_exp2f(S[0]);
            float p1  = __builtin_amdgcn_exp2f(S[1]);
            float p2  = __builtin_amdgcn_exp2f(S[2]);
            float p3  = __builtin_amdgcn_exp2f(S[3]);
            float p4  = __builtin_amdgcn_exp2f(S[4]);
            float p5  = __builtin_amdgcn_exp2f(S[5]);
            float p6  = __builtin_amdgcn_exp2f(S[6]);
            float p7  = __builtin_amdgcn_exp2f(S[7]);
            float p8  = __builtin_amdgcn_exp2f(S[8]);
            float p9  = __builtin_amdgcn_exp2f(S[9]);
            float p10 = __builtin_amdgcn_exp2f(S[10]);
            float p11 = __builtin_amdgcn_exp2f(S[11]);
            float p12 = __builtin_amdgcn_exp2f(S[12]);
            float p13 = __builtin_amdgcn_exp2f(S[13]);
            float p14 = __builtin_amdgcn_exp2f(S[14]);
            float p15 = __builtin_amdgcn_exp2f(S[15]);

            // denominator on VALU: packed-f32 add tree (7 pk-adds)
            f32x2 u0 = (f32x2){p0, p1} + (f32x2){p2, p3};
            f32x2 u1 = (f32x2){p4, p5} + (f32x2){p6, p7};
            f32x2 u2 = (f32x2){p8, p9} + (f32x2){p10, p11};
            f32x2 u3 = (f32x2){p12, p13} + (f32x2){p14, p15};
            l2 += (u0 + u1) + (u2 + u3);

            // B-frags: direct in-lane packs (pi makes k-order = reg-order)
            uint4 ub1 = make_uint4(pk_tr(p0, p1), pk_tr(p2, p3),
                                   pk_tr(p4, p5), pk_tr(p6, p7));
            uint4 ub2 = make_uint4(pk_tr(p8, p9), pk_tr(p10, p11),
                                   pk_tr(p12, p13), pk_tr(p14, p15));
            s16x8 B1 = *(s16x8*)&ub1;
            s16x8 B2 = *(s16x8*)&ub2;

            acc = __builtin_amdgcn_mfma_f32_32x32x16_bf16(G1, B1, acc, 0, 0, 0);
            acc = __builtin_amdgcn_mfma_f32_32x32x16_bf16(G2, B2, acc, 0, 0, 0);
        }
        __syncthreads();   // single barrier/st; drains next-st DMA (vmcnt) too
    }

    // per-half denominator: combine h-halves (h=0: m%8<4, h=1: rest)
    float l = l2[0] + l2[1];
    l += __shfl_xor(l, 32);

    // cross-half combine: half 1 dumps partials into now-free staging LDS
    int idx = (w4 << 6) + lane;          // 0..255, lane-aligned across halves
    if (hf == 1) {
        *(f32x16*)(smem + idx * 64) = acc;                 // [0,16384)
        *(float*)(smem + 32768 + idx * 4) = l;             // pA buf0, 1 KB
    }
    __syncthreads();
    if (hf == 0) {
        f32x16 accB = *(const f32x16*)(smem + idx * 64);
        float lB = *(const float*)(smem + 32768 + idx * 4);
        acc += accB;
        float linv = 1.0f / (l + lB);
        acc *= linv;

        // w_o A-frags: A[row=cc=16g4+nl][k=c=8q+j]
        s16x8 WO[4];
#pragma unroll
        for (int g4 = 0; g4 < 4; g4++) {
            const float4* wr = (const float4*)(w_o + (size_t)(g4 * 16 + nl) * 32 + q * 8);
            float4 a0 = wr[0], a1 = wr[1];
            WO[g4][0] = (short)f32_bf16(a0.x); WO[g4][1] = (short)f32_bf16(a0.y);
            WO[g4][2] = (short)f32_bf16(a0.z); WO[g4][3] = (short)f32_bf16(a0.w);
            WO[g4][4] = (short)f32_bf16(a1.x); WO[g4][5] = (short)f32_bf16(a1.y);
            WO[g4][6] = (short)f32_bf16(a1.z); WO[g4][7] = (short)f32_bf16(a1.w);
        }
        float gam = gamma[0];

        // O_s overlay [128][80 B] at 20480 (free; no overlap with dump/l regions)
        unsigned char* O_s = smem + 20480;
        int nloc = w4 * 32 + c31;
#pragma unroll
        for (int g2 = 0; g2 < 4; g2++) {
            uint2 ov;
            ov.x = pk_bf16(acc[4 * g2 + 0], acc[4 * g2 + 1]);
            ov.y = pk_bf16(acc[4 * g2 + 2], acc[4 * g2 + 3]);
            *(uint2*)(O_s + nloc * 80 + 16 * g2 + 8 * h) = ov;
        }
        int nloc0 = w4 * 32 + nl;
        int nloc1 = nloc0 + 16;
        s16x8 OB0 = *(const s16x8*)(O_s + nloc0 * 80 + q * 16);  // wave-local rows
        s16x8 OB1 = *(const s16x8*)(O_s + nloc1 * 80 + q * 16);
#pragma unroll
        for (int g4 = 0; g4 < 4; g4++) {
            f32x4 e0 = (f32x4){0.f, 0.f, 0.f, 0.f};
            f32x4 e1 = (f32x4){0.f, 0.f, 0.f, 0.f};
            e0 = __builtin_amdgcn_mfma_f32_16x16x32_bf16(WO[g4], OB0, e0, 0, 0, 0);
            e1 = __builtin_amdgcn_mfma_f32_16x16x32_bf16(WO[g4], OB1, e1, 0, 0, 0);
#pragma unroll
            for (int r = 0; r < 4; r++) {
                int cc = g4 * 16 + q * 4 + r;
                size_t gi0 = (((size_t)(b * 64 + cc)) << 14) + nw + nl;
                out[gi0] = gam * e0[r] + x[gi0];
                size_t gi1 = gi0 + 16;
                out[gi1] = gam * e1[r] + x[gi1];
            }
        }
    }
}

extern "C" void kernel_launch(void* const* d_in, const int* in_sizes, int n_in,
                              void* d_out, int out_size, void* d_ws, size_t ws_size,
                              hipStream_t stream) {
    const float* x       = (const float*)d_in[0];
    const float* w_theta = (const float*)d_in[1];
    const float* w_phi   = (const float*)d_in[2];
    const float* w_g     = (const float*)d_in[3];
    const float* w_o     = (const float*)d_in[4];
    const float* gamma   = (const float*)d_in[5];
    float* out = (float*)d_out;

    __hip_bfloat16* thG = (__hip_bfloat16*)d_ws;        // 4*16384*8 = 1 MB
    __hip_bfloat16* phG = thG + 524288;                 // 4*4096*8  = 256 KB
    __hip_bfloat16* gG  = phG + 131072;                 // 4*32*4096 = 1 MB

    proj_kernel<<<512, 256, 0, stream>>>(x, w_theta, w_phi, w_g, thG, phG, gG);
    attn_kernel<<<512, 512, 0, stream>>>(thG, phG, gG, w_o, gamma, x, out);
}